// Round 4
// baseline (198.891 us; speedup 1.0000x reference)
//
#include <hip/hip_runtime.h>
#include <hip/hip_cooperative_groups.h>
#include <math.h>

namespace cg = cooperative_groups;

namespace {

constexpr int DD = 1024;        // d
constexpr int NC = 3072;        // columns of x
constexpr int NG = 768;         // float4 groups per x row
constexpr int DG = 256;         // float4 groups per out row
constexpr int NROWS = 8192;     // B*T
constexpr int NCHUNK = 512;     // stat chunks (coop phase1 & fb col stats)
constexpr int FB_CH2 = 1024;    // fb main-pass chunks
constexpr int CGRID = 256;      // coop blocks (1 per CU -> always co-resident)
constexpr int CBLK = 512;       // coop block size (8 waves)
constexpr float GAMMA = 5.0f;
constexpr float EPS_NORM = 1e-5f;
constexpr float EPS_W = 1e-8f;
constexpr float ZCLAMP = 15.0f; // sigma(15)=1-3e-7

struct Params {
  const float *x;
  const float *wq, *aq, *gq, *betaq;
  const float *wk, *ak, *gk, *betak;
  const float *wv, *av, *gv, *betav;
  const float *g_out, *b_out;
  float *out;
  float *psum, *psq;     // [NCHUNK][NC] chunk-major
  float *A_arr, *B_arr;  // [3][NC]; gamma folded into q, col-mean folded into B
  float *opsum, *opsq;   // up to [FB_CH2][DD] chunk-major
  float *om, *osc, *ob;  // [DD]
  float *o_arr;          // [NROWS][DD] (fb big path only; may be null)
};

__device__ __forceinline__ void acc4(float4& s, float4& q, float4 v) {
  s.x += v.x; s.y += v.y; s.z += v.z; s.w += v.w;
  q.x += v.x * v.x; q.y += v.y * v.y; q.z += v.z * v.z; q.w += v.w * v.w;
}
__device__ __forceinline__ void add4(float4& s, float4 v) {
  s.x += v.x; s.y += v.y; s.z += v.z; s.w += v.w;
}

// Householder QR (LAPACK sign convention) of 3x3 a[d], write folded coefs.
__device__ __forceinline__ void qr_coef(const Params& P, int c, float mean, float var) {
  int p = c >> 10;            // 0=q,1=k,2=v
  int d = c & (DD - 1);
  const float* w    = (p == 0) ? P.wq    : (p == 1) ? P.wk    : P.wv;
  const float* a    = (p == 0) ? P.aq    : (p == 1) ? P.ak    : P.av;
  const float* g    = (p == 0) ? P.gq    : (p == 1) ? P.gk    : P.gv;
  const float* beta = (p == 0) ? P.betaq : (p == 1) ? P.betak : P.betav;
  float gam = (p == 0) ? GAMMA : 1.0f;

  float A[3][3];
  #pragma unroll
  for (int i = 0; i < 3; ++i)
    #pragma unroll
    for (int j = 0; j < 3; ++j) A[i][j] = a[(d * 3 + i) * 3 + j];

  float v1y = 0.f, v1z = 0.f, v2z = 0.f, t1 = 0.f, t2 = 0.f;
  {
    float alpha = A[0][0];
    float xn2 = A[1][0] * A[1][0] + A[2][0] * A[2][0];
    if (xn2 > 0.f) {
      float beta_ = -copysignf(sqrtf(alpha * alpha + xn2), alpha);
      t1 = (beta_ - alpha) / beta_;
      float inv = 1.0f / (alpha - beta_);
      v1y = A[1][0] * inv; v1z = A[2][0] * inv;
      #pragma unroll
      for (int j = 1; j < 3; ++j) {
        float dot = A[0][j] + A[1][j] * v1y + A[2][j] * v1z;
        float f = t1 * dot;
        A[0][j] -= f; A[1][j] -= f * v1y; A[2][j] -= f * v1z;
      }
    }
  }
  {
    float alpha = A[1][1], x2 = A[2][1];
    if (x2 != 0.f) {
      float beta_ = -copysignf(sqrtf(alpha * alpha + x2 * x2), alpha);
      t2 = (beta_ - alpha) / beta_;
      v2z = x2 / (alpha - beta_);
    }
  }
  float v1[3] = {1.f, v1y, v1z};
  float v2[3] = {0.f, 1.f, v2z};
  float v12 = v1y + v1z * v2z;
  float sp0 = log1pf(expf(w[d * 3 + 0]));
  float sp1 = log1pf(expf(w[d * 3 + 1]));
  float sp2 = log1pf(expf(w[d * 3 + 2]));
  #pragma unroll
  for (int j = 0; j < 3; ++j) {
    float Q0 = ((0 == j) ? 1.f : 0.f) - t1 * v1[0] * v1[j] - t2 * v2[0] * v2[j]
               + t1 * t2 * v12 * v1[0] * v2[j];
    float Q1 = ((1 == j) ? 1.f : 0.f) - t1 * v1[1] * v1[j] - t2 * v2[1] * v2[j]
               + t1 * t2 * v12 * v1[1] * v2[j];
    float Q2 = ((2 == j) ? 1.f : 0.f) - t1 * v1[2] * v1[j] - t2 * v2[2] * v2[j]
               + t1 * t2 * v12 * v1[2] * v2[j];
    float W = sp0 * Q0 + sp1 * Q1 + sp2 * Q2;
    float s = W * g[d * 3 + j] / sqrtf(W * W * var + EPS_NORM);
    P.A_arr[j * NC + c] = gam * s;
    P.B_arr[j * NC + c] = gam * (beta[d * 3 + j] - mean * s);
  }
}

struct CoefReg {
  float4 Aq[3], Bq[3], Ak[3], Bk[3], Av[3], Bv[3];
};

__device__ __forceinline__ CoefReg load_coefs(const Params& P, int tg) {
  CoefReg C;
  #pragma unroll
  for (int j = 0; j < 3; ++j) {
    C.Aq[j] = ((const float4*)(P.A_arr + j * NC))[tg];
    C.Ak[j] = ((const float4*)(P.A_arr + j * NC + DD))[tg];
    C.Av[j] = ((const float4*)(P.A_arr + j * NC + 2 * DD))[tg];
    C.Bq[j] = ((const float4*)(P.B_arr + j * NC))[tg];
    C.Bk[j] = ((const float4*)(P.B_arr + j * NC + DD))[tg];
    C.Bv[j] = ((const float4*)(P.B_arr + j * NC + 2 * DD))[tg];
  }
  return C;
}

__device__ __forceinline__ float4 contract4(float4 xq, float4 xk, float4 xv,
                                            const CoefReg& C) {
  float4 ov;
  #pragma unroll
  for (int kk = 0; kk < 4; ++kk) {
    float xqv = ((const float*)&xq)[kk];
    float xkv = ((const float*)&xk)[kk];
    float xvv = ((const float*)&xv)[kk];
    float Q[3], K[3], V[3];
    #pragma unroll
    for (int j = 0; j < 3; ++j) {
      Q[j] = fmaf(xqv, ((const float*)&C.Aq[j])[kk], ((const float*)&C.Bq[j])[kk]);
      K[j] = fmaf(xkv, ((const float*)&C.Ak[j])[kk], ((const float*)&C.Bk[j])[kk]);
      V[j] = fmaf(xvv, ((const float*)&C.Av[j])[kk], ((const float*)&C.Bv[j])[kk]);
    }
    // product form: multiply num & den by (1+e0)(1+e1)(1+e2); 3 exp + 1 div
    float e0 = __expf(fminf(Q[0] * K[0], ZCLAMP));
    float e1 = __expf(fminf(Q[1] * K[1], ZCLAMP));
    float e2 = __expf(fminf(Q[2] * K[2], ZCLAMP));
    float a0 = 1.f + e0, a1 = 1.f + e1, a2 = 1.f + e2;
    float a01 = a0 * a1, a12 = a1 * a2, a02 = a0 * a2;
    float w0 = e0 * a12, w1 = e1 * a02, w2 = e2 * a01;
    float num = w0 * V[0] + w1 * V[1] + w2 * V[2];
    float den = w0 + w1 + w2 + EPS_W * (a01 * a2);
    ((float*)&ov)[kk] = num / den;
  }
  return ov;
}

// ====================== cooperative single-kernel path ======================
// 256 blocks x 512 threads; 1 block/CU -> co-residency guaranteed.
__global__ __launch_bounds__(CBLK, 2) void fused_kernel(Params P) {
  cg::grid_group grid = cg::this_grid();
  const int b = blockIdx.x;
  const int t = threadIdx.x;
  const int th = t >> 8;           // row-half within block
  const int tg = t & 255;          // float4 d-group
  const int chunk = b * 2 + th;    // 0..511
  const int r0 = chunk * 16;       // 16 rows per chunk
  const float4* x4 = (const float4*)P.x;

  // ---- phase 1: per-column partial sum/sumsq ----
  {
    float4 s0 = {0,0,0,0}, s1 = {0,0,0,0}, s2 = {0,0,0,0};
    float4 q0 = {0,0,0,0}, q1 = {0,0,0,0}, q2 = {0,0,0,0};
    #pragma unroll
    for (int r = 0; r < 16; ++r) {
      size_t base = (size_t)(r0 + r) * NG;
      acc4(s0, q0, x4[base + tg]);
      acc4(s1, q1, x4[base + 256 + tg]);
      acc4(s2, q2, x4[base + 512 + tg]);
    }
    float4* ps4 = (float4*)(P.psum + (size_t)chunk * NC);
    float4* pq4 = (float4*)(P.psq + (size_t)chunk * NC);
    ps4[tg] = s0; ps4[256 + tg] = s1; ps4[512 + tg] = s2;
    pq4[tg] = q0; pq4[256 + tg] = q1; pq4[512 + tg] = q2;
  }
  grid.sync();

  // ---- phase 2: reduce col stats + QR -> folded coefs ----
  {
    int wid = b * 8 + (t >> 6);     // 0..2047
    int lane = t & 63;
    if (wid < NC / 2) {             // 1536 waves, 2 columns each
      int c = wid * 2 + (lane & 1);
      int pp = lane >> 1;           // 0..31
      float s = 0.f, q = 0.f;
      #pragma unroll 4
      for (int i = 0; i < 16; ++i) {
        int ch = pp * 16 + i;       // 0..511
        s += P.psum[(size_t)ch * NC + c];
        q += P.psq[(size_t)ch * NC + c];
      }
      #pragma unroll
      for (int off = 2; off <= 32; off <<= 1) {
        s += __shfl_xor(s, off);
        q += __shfl_xor(q, off);
      }
      if ((lane >> 1) == 0) {       // lanes 0,1 hold full sums
        float mean = s / NROWS;
        float var = q / NROWS - mean * mean;
        if (var < 0.f) var = 0.f;
        qr_coef(P, c, mean, var);
      }
    }
  }
  grid.sync();

  // ---- phase 3: contraction, o kept in registers, partial out-stats ----
  float4 osave[16];
  {
    CoefReg C = load_coefs(P, tg);
    float4 s = {0,0,0,0}, q = {0,0,0,0};
    #pragma unroll
    for (int r = 0; r < 16; ++r) {
      size_t base = (size_t)(r0 + r) * NG;
      float4 xq = x4[base + tg];
      float4 xk = x4[base + 256 + tg];
      float4 xv = x4[base + 512 + tg];
      float4 ov = contract4(xq, xk, xv, C);
      osave[r] = ov;
      acc4(s, q, ov);
    }
    ((float4*)P.opsum)[(size_t)chunk * DG + tg] = s;
    ((float4*)P.opsq)[(size_t)chunk * DG + tg] = q;
  }
  grid.sync();

  // ---- phase 4: out-column stats over 512 chunks ----
  {
    int wid = b * 8 + (t >> 6);
    int lane = t & 63;
    if (wid < DG) {                 // 256 waves, one float4 d-group each
      int g = wid;
      float4 s = {0,0,0,0}, q = {0,0,0,0};
      #pragma unroll 2
      for (int k = 0; k < 8; ++k) {
        int ch = lane + 64 * k;     // 0..511
        add4(s, ((const float4*)P.opsum)[(size_t)ch * DG + g]);
        add4(q, ((const float4*)P.opsq)[(size_t)ch * DG + g]);
      }
      #pragma unroll
      for (int off = 1; off <= 32; off <<= 1) {
        s.x += __shfl_xor(s.x, off); s.y += __shfl_xor(s.y, off);
        s.z += __shfl_xor(s.z, off); s.w += __shfl_xor(s.w, off);
        q.x += __shfl_xor(q.x, off); q.y += __shfl_xor(q.y, off);
        q.z += __shfl_xor(q.z, off); q.w += __shfl_xor(q.w, off);
      }
      if (lane == 0) {
        float4 go = ((const float4*)P.g_out)[g];
        float4 bo = ((const float4*)P.b_out)[g];
        float4 m, sc;
        float* mp = (float*)&m;
        float* scp = (float*)&sc;
        const float* sp = (const float*)&s;
        const float* qp = (const float*)&q;
        const float* gp = (const float*)&go;
        #pragma unroll
        for (int kk = 0; kk < 4; ++kk) {
          float mean = sp[kk] / NROWS;
          float var = qp[kk] / NROWS - mean * mean;
          if (var < 0.f) var = 0.f;
          mp[kk] = mean;
          scp[kk] = gp[kk] / sqrtf(var + EPS_NORM);
        }
        ((float4*)P.om)[g] = m;
        ((float4*)P.osc)[g] = sc;
        ((float4*)P.ob)[g] = bo;
      }
    }
  }
  grid.sync();

  // ---- phase 5: normalize registers, write out ----
  {
    float4 m = ((const float4*)P.om)[tg];
    float4 sc = ((const float4*)P.osc)[tg];
    float4 bb = ((const float4*)P.ob)[tg];
    float4* out4 = (float4*)P.out;
    #pragma unroll
    for (int r = 0; r < 16; ++r) {
      float4 o = osave[r];
      float4 y;
      y.x = (o.x - m.x) * sc.x + bb.x;
      y.y = (o.y - m.y) * sc.y + bb.y;
      y.z = (o.z - m.z) * sc.z + bb.z;
      y.w = (o.w - m.w) * sc.w + bb.w;
      out4[(size_t)(r0 + r) * DG + tg] = y;
    }
  }
}

// ====================== fallback multi-kernel path ======================
__global__ void fb_col_stats(const float* __restrict__ x,
                             float* __restrict__ psum, float* __restrict__ psq) {
  int cg_ = blockIdx.x * 256 + threadIdx.x;  // 0..767
  int chunk = blockIdx.y;                    // 0..511
  constexpr int rows_per = NROWS / NCHUNK;   // 16
  const float4* x4 = (const float4*)x;
  size_t base = (size_t)(chunk * rows_per) * NG + cg_;
  float4 s = {0,0,0,0}, q = {0,0,0,0};
  #pragma unroll
  for (int r = 0; r < rows_per; ++r) {
    float4 v = x4[base + (size_t)r * NG];
    acc4(s, q, v);
  }
  ((float4*)(psum + (size_t)chunk * NC))[cg_] = s;
  ((float4*)(psq + (size_t)chunk * NC))[cg_] = q;
}

__global__ void fb_coef(Params P) {
  int c = blockIdx.x;
  int lane = threadIdx.x;
  float s = 0.f, q = 0.f;
  #pragma unroll
  for (int k = 0; k < NCHUNK / 64; ++k) {
    int ch = lane + 64 * k;
    s += P.psum[(size_t)ch * NC + c];
    q += P.psq[(size_t)ch * NC + c];
  }
  #pragma unroll
  for (int off = 1; off <= 32; off <<= 1) {
    s += __shfl_xor(s, off);
    q += __shfl_xor(q, off);
  }
  if (lane != 0) return;
  float mean = s / NROWS;
  float var = q / NROWS - mean * mean;
  if (var < 0.f) var = 0.f;
  qr_coef(P, c, mean, var);
}

template <bool WRITE_O>
__global__ void fb_main(Params P) {
  int t = threadIdx.x;              // 0..255
  int chunk = blockIdx.x;           // 0..FB_CH2-1
  constexpr int rows_per = NROWS / FB_CH2;  // 8
  CoefReg C = load_coefs(P, t);
  const float4* x4 = (const float4*)P.x;
  float4 s = {0,0,0,0}, q = {0,0,0,0};
  int r0 = chunk * rows_per;
  #pragma unroll
  for (int r = 0; r < rows_per; ++r) {
    size_t base = (size_t)(r0 + r) * NG;
    float4 xq = x4[base + t];
    float4 xk = x4[base + 256 + t];
    float4 xv = x4[base + 512 + t];
    float4 ov = contract4(xq, xk, xv, C);
    acc4(s, q, ov);
    if (WRITE_O) ((float4*)P.o_arr)[(size_t)(r0 + r) * DG + t] = ov;
  }
  ((float4*)P.opsum)[(size_t)chunk * DG + t] = s;
  ((float4*)P.opsq)[(size_t)chunk * DG + t] = q;
}

__global__ void fb_out_stats(Params P) {
  int d = blockIdx.x;               // 0..1023
  int lane = threadIdx.x;
  float s = 0.f, q = 0.f;
  #pragma unroll
  for (int k = 0; k < FB_CH2 / 64; ++k) {
    int ch = lane + 64 * k;
    s += P.opsum[(size_t)ch * DD + d];
    q += P.opsq[(size_t)ch * DD + d];
  }
  #pragma unroll
  for (int off = 1; off <= 32; off <<= 1) {
    s += __shfl_xor(s, off);
    q += __shfl_xor(q, off);
  }
  if (lane != 0) return;
  float mean = s / NROWS;
  float var = q / NROWS - mean * mean;
  if (var < 0.f) var = 0.f;
  P.om[d] = mean;
  P.osc[d] = P.g_out[d] / sqrtf(var + EPS_NORM);
  P.ob[d] = P.b_out[d];
}

__global__ void fb_final_from_o(Params P) {
  int t = threadIdx.x;
  int r0 = blockIdx.x * 4;
  float4 m = ((const float4*)P.om)[t];
  float4 sc = ((const float4*)P.osc)[t];
  float4 bb = ((const float4*)P.ob)[t];
  float4* out4 = (float4*)P.out;
  const float4* o4 = (const float4*)P.o_arr;
  #pragma unroll
  for (int rr = 0; rr < 4; ++rr) {
    size_t idx = (size_t)(r0 + rr) * DG + t;
    float4 o = o4[idx];
    float4 y;
    y.x = (o.x - m.x) * sc.x + bb.x;
    y.y = (o.y - m.y) * sc.y + bb.y;
    y.z = (o.z - m.z) * sc.z + bb.z;
    y.w = (o.w - m.w) * sc.w + bb.w;
    out4[idx] = y;
  }
}

__global__ void fb_final_recompute(Params P) {
  int t = threadIdx.x;
  int chunk = blockIdx.x;           // 0..511
  constexpr int rows_per = NROWS / 512;  // 16
  CoefReg C = load_coefs(P, t);
  const float4* x4 = (const float4*)P.x;
  float4 m = ((const float4*)P.om)[t];
  float4 sc = ((const float4*)P.osc)[t];
  float4 bb = ((const float4*)P.ob)[t];
  float4* out4 = (float4*)P.out;
  int r0 = chunk * rows_per;
  for (int r = r0; r < r0 + rows_per; ++r) {
    size_t base = (size_t)r * NG;
    float4 xq = x4[base + t];
    float4 xk = x4[base + 256 + t];
    float4 xv = x4[base + 512 + t];
    float4 o = contract4(xq, xk, xv, C);
    float4 y;
    y.x = (o.x - m.x) * sc.x + bb.x;
    y.y = (o.y - m.y) * sc.y + bb.y;
    y.z = (o.z - m.z) * sc.z + bb.z;
    y.w = (o.w - m.w) * sc.w + bb.w;
    out4[(size_t)r * DG + t] = y;
  }
}

}  // namespace

extern "C" void kernel_launch(void* const* d_in, const int* in_sizes, int n_in,
                              void* d_out, int out_size, void* d_ws, size_t ws_size,
                              hipStream_t stream) {
  Params P;
  P.x     = (const float*)d_in[0];
  P.wq    = (const float*)d_in[1];
  P.aq    = (const float*)d_in[3];
  P.gq    = (const float*)d_in[4];
  P.betaq = (const float*)d_in[5];
  P.wk    = (const float*)d_in[6];
  P.ak    = (const float*)d_in[8];
  P.gk    = (const float*)d_in[9];
  P.betak = (const float*)d_in[10];
  P.wv    = (const float*)d_in[11];
  P.av    = (const float*)d_in[13];
  P.gv    = (const float*)d_in[14];
  P.betav = (const float*)d_in[15];
  P.g_out = (const float*)d_in[16];
  P.b_out = (const float*)d_in[17];
  P.out   = (float*)d_out;

  float* ws = (float*)d_ws;
  P.psum  = ws;  ws += (size_t)NCHUNK * NC;    // 6.3 MB
  P.psq   = ws;  ws += (size_t)NCHUNK * NC;    // 6.3 MB
  P.A_arr = ws;  ws += 3 * NC;
  P.B_arr = ws;  ws += 3 * NC;
  P.opsum = ws;  ws += (size_t)FB_CH2 * DD;    // 4 MB
  P.opsq  = ws;  ws += (size_t)FB_CH2 * DD;    // 4 MB
  P.om    = ws;  ws += DD;
  P.osc   = ws;  ws += DD;
  P.ob    = ws;  ws += DD;
  size_t used_bytes = (size_t)((char*)ws - (char*)d_ws);
  size_t o_bytes = (size_t)NROWS * DD * sizeof(float);  // 32 MB
  bool have_o = (ws_size >= used_bytes + o_bytes);
  P.o_arr = have_o ? ws : nullptr;

  // ---- try cooperative single-kernel path; fall back on launch error ----
  void* kargs[] = {(void*)&P};
  hipError_t err = hipLaunchCooperativeKernel((const void*)fused_kernel,
                                              dim3(CGRID), dim3(CBLK),
                                              kargs, 0, stream);
  if (err == hipSuccess) return;
  (void)hipGetLastError();  // clear sticky error state

  // ---- fallback: 5-kernel pipeline ----
  fb_col_stats<<<dim3(NG / 256, NCHUNK), dim3(256), 0, stream>>>(P.x, P.psum, P.psq);
  fb_coef<<<dim3(NC), dim3(64), 0, stream>>>(P);
  if (have_o) {
    fb_main<true><<<dim3(FB_CH2), dim3(256), 0, stream>>>(P);
    fb_out_stats<<<dim3(DD), dim3(64), 0, stream>>>(P);
    fb_final_from_o<<<dim3(NROWS / 4), dim3(256), 0, stream>>>(P);
  } else {
    fb_main<false><<<dim3(FB_CH2), dim3(256), 0, stream>>>(P);
    fb_out_stats<<<dim3(DD), dim3(64), 0, stream>>>(P);
    fb_final_recompute<<<dim3(512), dim3(256), 0, stream>>>(P);
  }
}

// Round 5
// 66.252 us; speedup vs baseline: 3.0020x; 3.0020x over previous
//
#include <hip/hip_runtime.h>
#include <math.h>

namespace {

constexpr int DD = 1024;        // d
constexpr int NC = 3072;        // columns of x
constexpr int NG = 768;         // float4 groups per x row
constexpr int DG = 256;         // float4 groups per out row
constexpr int NROWS = 8192;     // B*T
constexpr int CH1 = 64;         // col-stat chunks (after intra-block reduce)
constexpr int CH2 = 256;        // out-stat chunks (after intra-block reduce)
constexpr float GAMMA = 5.0f;
constexpr float EPS_NORM = 1e-5f;
constexpr float EPS_W = 1e-8f;
constexpr float ZCLAMP = 15.0f; // sigma(15)=1-3e-7

struct Params {
  const float *x;
  const float *wq, *aq, *gq, *betaq;
  const float *wk, *ak, *gk, *betak;
  const float *wv, *av, *gv, *betav;
  const float *g_out, *b_out;
  float *out;
  float *psum, *psq;     // [CH1][NC]
  float *A_arr, *B_arr;  // [3][NC]; gamma folded into q, col-mean folded into B
  float *opsum, *opsq;   // [CH2][DD]
  float *om, *osc, *ob;  // [DD]
  float *o_arr;          // [NROWS][DD]
};

__device__ __forceinline__ void acc4(float4& s, float4& q, float4 v) {
  s.x += v.x; s.y += v.y; s.z += v.z; s.w += v.w;
  q.x += v.x * v.x; q.y += v.y * v.y; q.z += v.z * v.z; q.w += v.w * v.w;
}
__device__ __forceinline__ void add4(float4& s, float4 v) {
  s.x += v.x; s.y += v.y; s.z += v.z; s.w += v.w;
}

// Householder QR (LAPACK sign convention) of 3x3 a[d]; write folded coefs.
__device__ __forceinline__ void qr_coef(const Params& P, int c, float mean, float var) {
  int p = c >> 10;            // 0=q,1=k,2=v
  int d = c & (DD - 1);
  const float* w    = (p == 0) ? P.wq    : (p == 1) ? P.wk    : P.wv;
  const float* a    = (p == 0) ? P.aq    : (p == 1) ? P.ak    : P.av;
  const float* g    = (p == 0) ? P.gq    : (p == 1) ? P.gk    : P.gv;
  const float* beta = (p == 0) ? P.betaq : (p == 1) ? P.betak : P.betav;
  float gam = (p == 0) ? GAMMA : 1.0f;

  float A[3][3];
  #pragma unroll
  for (int i = 0; i < 3; ++i)
    #pragma unroll
    for (int j = 0; j < 3; ++j) A[i][j] = a[(d * 3 + i) * 3 + j];

  float v1y = 0.f, v1z = 0.f, v2z = 0.f, t1 = 0.f, t2 = 0.f;
  {
    float alpha = A[0][0];
    float xn2 = A[1][0] * A[1][0] + A[2][0] * A[2][0];
    if (xn2 > 0.f) {
      float beta_ = -copysignf(sqrtf(alpha * alpha + xn2), alpha);
      t1 = (beta_ - alpha) / beta_;
      float inv = 1.0f / (alpha - beta_);
      v1y = A[1][0] * inv; v1z = A[2][0] * inv;
      #pragma unroll
      for (int j = 1; j < 3; ++j) {
        float dot = A[0][j] + A[1][j] * v1y + A[2][j] * v1z;
        float f = t1 * dot;
        A[0][j] -= f; A[1][j] -= f * v1y; A[2][j] -= f * v1z;
      }
    }
  }
  {
    float alpha = A[1][1], x2 = A[2][1];
    if (x2 != 0.f) {
      float beta_ = -copysignf(sqrtf(alpha * alpha + x2 * x2), alpha);
      t2 = (beta_ - alpha) / beta_;
      v2z = x2 / (alpha - beta_);
    }
  }
  float v1[3] = {1.f, v1y, v1z};
  float v2[3] = {0.f, 1.f, v2z};
  float v12 = v1y + v1z * v2z;
  float sp0 = log1pf(expf(w[d * 3 + 0]));
  float sp1 = log1pf(expf(w[d * 3 + 1]));
  float sp2 = log1pf(expf(w[d * 3 + 2]));
  #pragma unroll
  for (int j = 0; j < 3; ++j) {
    float Q0 = ((0 == j) ? 1.f : 0.f) - t1 * v1[0] * v1[j] - t2 * v2[0] * v2[j]
               + t1 * t2 * v12 * v1[0] * v2[j];
    float Q1 = ((1 == j) ? 1.f : 0.f) - t1 * v1[1] * v1[j] - t2 * v2[1] * v2[j]
               + t1 * t2 * v12 * v1[1] * v2[j];
    float Q2 = ((2 == j) ? 1.f : 0.f) - t1 * v1[2] * v1[j] - t2 * v2[2] * v2[j]
               + t1 * t2 * v12 * v1[2] * v2[j];
    float W = sp0 * Q0 + sp1 * Q1 + sp2 * Q2;
    float s = W * g[d * 3 + j] / sqrtf(W * W * var + EPS_NORM);
    P.A_arr[j * NC + c] = gam * s;
    P.B_arr[j * NC + c] = gam * (beta[d * 3 + j] - mean * s);
  }
}

struct CoefReg {
  float4 Aq[3], Bq[3], Ak[3], Bk[3], Av[3], Bv[3];
};

__device__ __forceinline__ CoefReg load_coefs(const Params& P, int tg) {
  CoefReg C;
  #pragma unroll
  for (int j = 0; j < 3; ++j) {
    C.Aq[j] = ((const float4*)(P.A_arr + j * NC))[tg];
    C.Ak[j] = ((const float4*)(P.A_arr + j * NC + DD))[tg];
    C.Av[j] = ((const float4*)(P.A_arr + j * NC + 2 * DD))[tg];
    C.Bq[j] = ((const float4*)(P.B_arr + j * NC))[tg];
    C.Bk[j] = ((const float4*)(P.B_arr + j * NC + DD))[tg];
    C.Bv[j] = ((const float4*)(P.B_arr + j * NC + 2 * DD))[tg];
  }
  return C;
}

__device__ __forceinline__ float4 contract4(float4 xq, float4 xk, float4 xv,
                                            const CoefReg& C) {
  float4 ov;
  #pragma unroll
  for (int kk = 0; kk < 4; ++kk) {
    float xqv = ((const float*)&xq)[kk];
    float xkv = ((const float*)&xk)[kk];
    float xvv = ((const float*)&xv)[kk];
    float Q[3], K[3], V[3];
    #pragma unroll
    for (int j = 0; j < 3; ++j) {
      Q[j] = fmaf(xqv, ((const float*)&C.Aq[j])[kk], ((const float*)&C.Bq[j])[kk]);
      K[j] = fmaf(xkv, ((const float*)&C.Ak[j])[kk], ((const float*)&C.Bk[j])[kk]);
      V[j] = fmaf(xvv, ((const float*)&C.Av[j])[kk], ((const float*)&C.Bv[j])[kk]);
    }
    // product form: multiply num & den by (1+e0)(1+e1)(1+e2); 3 exp + 1 div
    float e0 = __expf(fminf(Q[0] * K[0], ZCLAMP));
    float e1 = __expf(fminf(Q[1] * K[1], ZCLAMP));
    float e2 = __expf(fminf(Q[2] * K[2], ZCLAMP));
    float a0 = 1.f + e0, a1 = 1.f + e1, a2 = 1.f + e2;
    float a01 = a0 * a1, a12 = a1 * a2, a02 = a0 * a2;
    float w0 = e0 * a12, w1 = e1 * a02, w2 = e2 * a01;
    float num = w0 * V[0] + w1 * V[1] + w2 * V[2];
    float den = w0 + w1 + w2 + EPS_W * (a01 * a2);
    ((float*)&ov)[kk] = num / den;
  }
  return ov;
}

// ============ K1: col stats. grid (12, 64), block 256 (4 waves) ============
// block: 64 float4-col-groups x 128 rows; LDS-reduce 4 row-slices -> 1 chunk.
__global__ __launch_bounds__(256, 4) void k1_col_stats(Params P) {
  __shared__ float4 lds_s[4][64];
  __shared__ float4 lds_q[4][64];
  const int t = threadIdx.x;
  const int lane = t & 63;
  const int slice = t >> 6;               // 0..3
  const int cg = blockIdx.x * 64 + lane;  // float4 col group 0..767
  const int r0 = blockIdx.y * 128 + slice * 32;
  const float4* x4 = (const float4*)P.x;
  float4 s = {0,0,0,0}, q = {0,0,0,0};
  #pragma unroll 8
  for (int r = 0; r < 32; ++r) {
    acc4(s, q, x4[(size_t)(r0 + r) * NG + cg]);
  }
  lds_s[slice][lane] = s;
  lds_q[slice][lane] = q;
  __syncthreads();
  if (t < 64) {
    float4 ss = lds_s[0][t], qq = lds_q[0][t];
    #pragma unroll
    for (int i = 1; i < 4; ++i) { add4(ss, lds_s[i][t]); add4(qq, lds_q[i][t]); }
    ((float4*)(P.psum + (size_t)blockIdx.y * NC))[blockIdx.x * 64 + t] = ss;
    ((float4*)(P.psq + (size_t)blockIdx.y * NC))[blockIdx.x * 64 + t] = qq;
  }
}

// ============ K2: reduce stats + QR. grid 48, block 256 ============
// block: 64 cols; lanes = cols (coalesced); 4 chunk-slices of 16.
__global__ __launch_bounds__(256, 4) void k2_coef(Params P) {
  __shared__ float lds_s[4][64];
  __shared__ float lds_q[4][64];
  const int t = threadIdx.x;
  const int lane = t & 63;
  const int slice = t >> 6;
  const int c = blockIdx.x * 64 + lane;   // 0..3071
  float s = 0.f, q = 0.f;
  #pragma unroll
  for (int i = 0; i < 16; ++i) {
    int ch = slice * 16 + i;              // 0..63
    s += P.psum[(size_t)ch * NC + c];
    q += P.psq[(size_t)ch * NC + c];
  }
  lds_s[slice][lane] = s;
  lds_q[slice][lane] = q;
  __syncthreads();
  if (t < 64) {
    float ss = lds_s[0][t] + lds_s[1][t] + lds_s[2][t] + lds_s[3][t];
    float qq = lds_q[0][t] + lds_q[1][t] + lds_q[2][t] + lds_q[3][t];
    float mean = ss / NROWS;
    float var = qq / NROWS - mean * mean;
    if (var < 0.f) var = 0.f;
    qr_coef(P, blockIdx.x * 64 + t, mean, var);
  }
}

// ============ K3: contraction + store o + partial out-stats ============
// grid (4, 256), block 256 (4 waves). block: 64 d-groups x 32 rows.
__global__ __launch_bounds__(256, 3) void k3_main(Params P) {
  __shared__ float4 lds_s[4][64];
  __shared__ float4 lds_q[4][64];
  const int t = threadIdx.x;
  const int lane = t & 63;
  const int slice = t >> 6;
  const int tg = blockIdx.x * 64 + lane;  // float4 d-group 0..255
  const int r0 = blockIdx.y * 32 + slice * 8;
  const float4* x4 = (const float4*)P.x;
  float4* o4 = (float4*)P.o_arr;
  CoefReg C = load_coefs(P, tg);
  float4 s = {0,0,0,0}, q = {0,0,0,0};
  #pragma unroll
  for (int r = 0; r < 8; ++r) {
    size_t base = (size_t)(r0 + r) * NG;
    float4 xq = x4[base + tg];
    float4 xk = x4[base + 256 + tg];
    float4 xv = x4[base + 512 + tg];
    float4 ov = contract4(xq, xk, xv, C);
    o4[(size_t)(r0 + r) * DG + tg] = ov;
    acc4(s, q, ov);
  }
  lds_s[slice][lane] = s;
  lds_q[slice][lane] = q;
  __syncthreads();
  if (t < 64) {
    float4 ss = lds_s[0][t], qq = lds_q[0][t];
    #pragma unroll
    for (int i = 1; i < 4; ++i) { add4(ss, lds_s[i][t]); add4(qq, lds_q[i][t]); }
    ((float4*)(P.opsum + (size_t)blockIdx.y * DD))[blockIdx.x * 64 + t] = ss;
    ((float4*)(P.opsq + (size_t)blockIdx.y * DD))[blockIdx.x * 64 + t] = qq;
  }
}

// ============ K4: out stats. grid 16, block 256 ============
// block: 64 cols; 4 chunk-slices of 64 chunks.
__global__ __launch_bounds__(256, 4) void k4_out_stats(Params P) {
  __shared__ float lds_s[4][64];
  __shared__ float lds_q[4][64];
  const int t = threadIdx.x;
  const int lane = t & 63;
  const int slice = t >> 6;
  const int d = blockIdx.x * 64 + lane;   // 0..1023
  float s = 0.f, q = 0.f;
  #pragma unroll 8
  for (int i = 0; i < 64; ++i) {
    int ch = slice * 64 + i;              // 0..255
    s += P.opsum[(size_t)ch * DD + d];
    q += P.opsq[(size_t)ch * DD + d];
  }
  lds_s[slice][lane] = s;
  lds_q[slice][lane] = q;
  __syncthreads();
  if (t < 64) {
    int dd = blockIdx.x * 64 + t;
    float ss = lds_s[0][t] + lds_s[1][t] + lds_s[2][t] + lds_s[3][t];
    float qq = lds_q[0][t] + lds_q[1][t] + lds_q[2][t] + lds_q[3][t];
    float mean = ss / NROWS;
    float var = qq / NROWS - mean * mean;
    if (var < 0.f) var = 0.f;
    P.om[dd] = mean;
    P.osc[dd] = P.g_out[dd] / sqrtf(var + EPS_NORM);
    P.ob[dd] = P.b_out[dd];
  }
}

// ============ K5: normalize + write. grid 2048, block 256 ============
__global__ __launch_bounds__(256, 8) void k5_final(Params P) {
  const int t = threadIdx.x;
  const int r0 = blockIdx.x * 4;
  float4 m = ((const float4*)P.om)[t];
  float4 sc = ((const float4*)P.osc)[t];
  float4 bb = ((const float4*)P.ob)[t];
  const float4* o4 = (const float4*)P.o_arr;
  float4* out4 = (float4*)P.out;
  #pragma unroll
  for (int rr = 0; rr < 4; ++rr) {
    size_t idx = (size_t)(r0 + rr) * DG + t;
    float4 o = o4[idx];
    float4 y;
    y.x = (o.x - m.x) * sc.x + bb.x;
    y.y = (o.y - m.y) * sc.y + bb.y;
    y.z = (o.z - m.z) * sc.z + bb.z;
    y.w = (o.w - m.w) * sc.w + bb.w;
    out4[idx] = y;
  }
}

}  // namespace

extern "C" void kernel_launch(void* const* d_in, const int* in_sizes, int n_in,
                              void* d_out, int out_size, void* d_ws, size_t ws_size,
                              hipStream_t stream) {
  Params P;
  P.x     = (const float*)d_in[0];
  P.wq    = (const float*)d_in[1];
  P.aq    = (const float*)d_in[3];
  P.gq    = (const float*)d_in[4];
  P.betaq = (const float*)d_in[5];
  P.wk    = (const float*)d_in[6];
  P.ak    = (const float*)d_in[8];
  P.gk    = (const float*)d_in[9];
  P.betak = (const float*)d_in[10];
  P.wv    = (const float*)d_in[11];
  P.av    = (const float*)d_in[13];
  P.gv    = (const float*)d_in[14];
  P.betav = (const float*)d_in[15];
  P.g_out = (const float*)d_in[16];
  P.b_out = (const float*)d_in[17];
  P.out   = (float*)d_out;

  float* ws = (float*)d_ws;
  P.psum  = ws;  ws += (size_t)CH1 * NC;     // 0.79 MB
  P.psq   = ws;  ws += (size_t)CH1 * NC;     // 0.79 MB
  P.A_arr = ws;  ws += 3 * NC;
  P.B_arr = ws;  ws += 3 * NC;
  P.opsum = ws;  ws += (size_t)CH2 * DD;     // 1 MB
  P.opsq  = ws;  ws += (size_t)CH2 * DD;     // 1 MB
  P.om    = ws;  ws += DD;
  P.osc   = ws;  ws += DD;
  P.ob    = ws;  ws += DD;
  P.o_arr = ws;  ws += (size_t)NROWS * DD;   // 32 MB

  k1_col_stats<<<dim3(12, 64), dim3(256), 0, stream>>>(P);
  k2_coef<<<dim3(48), dim3(256), 0, stream>>>(P);
  k3_main<<<dim3(4, 256), dim3(256), 0, stream>>>(P);
  k4_out_stats<<<dim3(16), dim3(256), 0, stream>>>(P);
  k5_final<<<dim3(2048), dim3(256), 0, stream>>>(P);
}

// Round 7
// 64.199 us; speedup vs baseline: 3.0981x; 1.0320x over previous
//
#include <hip/hip_runtime.h>
#include <math.h>

namespace {

constexpr int DD = 1024;        // d
constexpr int NC = 3072;        // columns of x
constexpr int NG = 768;         // float4 groups per x row
constexpr int DG = 256;         // float4 groups per out row
constexpr int NROWS = 8192;     // B*T
constexpr float GAMMA = 5.0f;
constexpr float EPS_NORM = 1e-5f;
constexpr float EPS_W = 1e-8f;
constexpr float ZCLAMP = 15.0f; // sigma(15)=1-3e-7

typedef float nfloat4 __attribute__((ext_vector_type(4)));

struct Params {
  const float *x;
  const float *wq, *aq, *gq, *betaq;
  const float *wk, *ak, *gk, *betak;
  const float *wv, *av, *gv, *betav;
  const float *g_out, *b_out;
  float *out;
  float *colsum, *colsq;  // [NC] atomically accumulated
  float *A_arr, *B_arr;   // [3][NC]; gamma folded into q, col-mean folded into B
  float *osum, *osq;      // [DD] atomically accumulated
  float *o_arr;           // [NROWS][DD]
};

__device__ __forceinline__ void acc4(float4& s, float4& q, float4 v) {
  s.x += v.x; s.y += v.y; s.z += v.z; s.w += v.w;
  q.x += v.x * v.x; q.y += v.y * v.y; q.z += v.z * v.z; q.w += v.w * v.w;
}

// Householder QR (LAPACK sign convention) of 3x3 a[d]; write folded coefs.
__device__ __forceinline__ void qr_coef(const Params& P, int c, float mean, float var) {
  int p = c >> 10;            // 0=q,1=k,2=v
  int d = c & (DD - 1);
  const float* w    = (p == 0) ? P.wq    : (p == 1) ? P.wk    : P.wv;
  const float* a    = (p == 0) ? P.aq    : (p == 1) ? P.ak    : P.av;
  const float* g    = (p == 0) ? P.gq    : (p == 1) ? P.gk    : P.gv;
  const float* beta = (p == 0) ? P.betaq : (p == 1) ? P.betak : P.betav;
  float gam = (p == 0) ? GAMMA : 1.0f;

  float A[3][3];
  #pragma unroll
  for (int i = 0; i < 3; ++i)
    #pragma unroll
    for (int j = 0; j < 3; ++j) A[i][j] = a[(d * 3 + i) * 3 + j];

  float v1y = 0.f, v1z = 0.f, v2z = 0.f, t1 = 0.f, t2 = 0.f;
  {
    float alpha = A[0][0];
    float xn2 = A[1][0] * A[1][0] + A[2][0] * A[2][0];
    if (xn2 > 0.f) {
      float beta_ = -copysignf(sqrtf(alpha * alpha + xn2), alpha);
      t1 = (beta_ - alpha) / beta_;
      float inv = 1.0f / (alpha - beta_);
      v1y = A[1][0] * inv; v1z = A[2][0] * inv;
      #pragma unroll
      for (int j = 1; j < 3; ++j) {
        float dot = A[0][j] + A[1][j] * v1y + A[2][j] * v1z;
        float f = t1 * dot;
        A[0][j] -= f; A[1][j] -= f * v1y; A[2][j] -= f * v1z;
      }
    }
  }
  {
    float alpha = A[1][1], x2 = A[2][1];
    if (x2 != 0.f) {
      float beta_ = -copysignf(sqrtf(alpha * alpha + x2 * x2), alpha);
      t2 = (beta_ - alpha) / beta_;
      v2z = x2 / (alpha - beta_);
    }
  }
  float v1[3] = {1.f, v1y, v1z};
  float v2[3] = {0.f, 1.f, v2z};
  float v12 = v1y + v1z * v2z;
  float sp0 = log1pf(expf(w[d * 3 + 0]));
  float sp1 = log1pf(expf(w[d * 3 + 1]));
  float sp2 = log1pf(expf(w[d * 3 + 2]));
  #pragma unroll
  for (int j = 0; j < 3; ++j) {
    float Q0 = ((0 == j) ? 1.f : 0.f) - t1 * v1[0] * v1[j] - t2 * v2[0] * v2[j]
               + t1 * t2 * v12 * v1[0] * v2[j];
    float Q1 = ((1 == j) ? 1.f : 0.f) - t1 * v1[1] * v1[j] - t2 * v2[1] * v2[j]
               + t1 * t2 * v12 * v1[1] * v2[j];
    float Q2 = ((2 == j) ? 1.f : 0.f) - t1 * v1[2] * v1[j] - t2 * v2[2] * v2[j]
               + t1 * t2 * v12 * v1[2] * v2[j];
    float W = sp0 * Q0 + sp1 * Q1 + sp2 * Q2;
    float s = W * g[d * 3 + j] / sqrtf(W * W * var + EPS_NORM);
    P.A_arr[j * NC + c] = gam * s;
    P.B_arr[j * NC + c] = gam * (beta[d * 3 + j] - mean * s);
  }
}

struct CoefReg {
  float4 Aq[3], Bq[3], Ak[3], Bk[3], Av[3], Bv[3];
};

__device__ __forceinline__ CoefReg load_coefs(const Params& P, int tg) {
  CoefReg C;
  #pragma unroll
  for (int j = 0; j < 3; ++j) {
    C.Aq[j] = ((const float4*)(P.A_arr + j * NC))[tg];
    C.Ak[j] = ((const float4*)(P.A_arr + j * NC + DD))[tg];
    C.Av[j] = ((const float4*)(P.A_arr + j * NC + 2 * DD))[tg];
    C.Bq[j] = ((const float4*)(P.B_arr + j * NC))[tg];
    C.Bk[j] = ((const float4*)(P.B_arr + j * NC + DD))[tg];
    C.Bv[j] = ((const float4*)(P.B_arr + j * NC + 2 * DD))[tg];
  }
  return C;
}

__device__ __forceinline__ float4 contract4(float4 xq, float4 xk, float4 xv,
                                            const CoefReg& C) {
  float4 ov;
  #pragma unroll
  for (int kk = 0; kk < 4; ++kk) {
    float xqv = ((const float*)&xq)[kk];
    float xkv = ((const float*)&xk)[kk];
    float xvv = ((const float*)&xv)[kk];
    float Q[3], K[3], V[3];
    #pragma unroll
    for (int j = 0; j < 3; ++j) {
      Q[j] = fmaf(xqv, ((const float*)&C.Aq[j])[kk], ((const float*)&C.Bq[j])[kk]);
      K[j] = fmaf(xkv, ((const float*)&C.Ak[j])[kk], ((const float*)&C.Bk[j])[kk]);
      V[j] = fmaf(xvv, ((const float*)&C.Av[j])[kk], ((const float*)&C.Bv[j])[kk]);
    }
    // product form: multiply num & den by (1+e0)(1+e1)(1+e2); 3 exp + 1 div
    float e0 = __expf(fminf(Q[0] * K[0], ZCLAMP));
    float e1 = __expf(fminf(Q[1] * K[1], ZCLAMP));
    float e2 = __expf(fminf(Q[2] * K[2], ZCLAMP));
    float a0 = 1.f + e0, a1 = 1.f + e1, a2 = 1.f + e2;
    float a01 = a0 * a1, a12 = a1 * a2, a02 = a0 * a2;
    float w0 = e0 * a12, w1 = e1 * a02, w2 = e2 * a01;
    float num = w0 * V[0] + w1 * V[1] + w2 * V[2];
    float den = w0 + w1 + w2 + EPS_W * (a01 * a2);
    ((float*)&ov)[kk] = num / den;
  }
  return ov;
}

// ============ K1: col stats -> atomic accumulators. grid (12,64) ============
// block: 64 float4-col-groups x 128 rows; LDS-reduce, 1 atomicAdd pair/thread.
__global__ __launch_bounds__(256, 4) void k1_col_stats(Params P) {
  __shared__ float4 lds_s[4][64];
  __shared__ float4 lds_q[4][64];
  const int t = threadIdx.x;
  const int lane = t & 63;
  const int slice = t >> 6;               // 0..3
  const int cg = blockIdx.x * 64 + lane;  // float4 col group 0..767
  const int r0 = blockIdx.y * 128 + slice * 32;
  const float4* x4 = (const float4*)P.x;
  float4 s = {0,0,0,0}, q = {0,0,0,0};
  #pragma unroll 8
  for (int r = 0; r < 32; ++r) {
    acc4(s, q, x4[(size_t)(r0 + r) * NG + cg]);
  }
  lds_s[slice][lane] = s;
  lds_q[slice][lane] = q;
  __syncthreads();
  // thread t owns scalar column c = blockIdx.x*256 + t
  float ssum = 0.f, ssq = 0.f;
  #pragma unroll
  for (int i = 0; i < 4; ++i) {
    ssum += ((const float*)&lds_s[i][t >> 2])[t & 3];
    ssq  += ((const float*)&lds_q[i][t >> 2])[t & 3];
  }
  atomicAdd(&P.colsum[blockIdx.x * 256 + t], ssum);
  atomicAdd(&P.colsq[blockIdx.x * 256 + t], ssq);
}

// ============ K2: QR + fold coefs. grid 12, block 256; 1 col/thread ============
__global__ __launch_bounds__(256, 4) void k2_coef(Params P) {
  const int c = blockIdx.x * 256 + threadIdx.x;  // 0..3071
  float s = P.colsum[c];
  float q = P.colsq[c];
  float mean = s / NROWS;
  float var = q / NROWS - mean * mean;
  if (var < 0.f) var = 0.f;
  qr_coef(P, c, mean, var);
}

// ============ K3: contraction + store o + atomic out-stats ============
// grid (4, 256), block 256 (4 waves). block: 64 d-groups x 32 rows.
__global__ __launch_bounds__(256, 3) void k3_main(Params P) {
  __shared__ float4 lds_s[4][64];
  __shared__ float4 lds_q[4][64];
  const int t = threadIdx.x;
  const int lane = t & 63;
  const int slice = t >> 6;
  const int tg = blockIdx.x * 64 + lane;  // float4 d-group 0..255
  const int r0 = blockIdx.y * 32 + slice * 8;
  const float4* x4 = (const float4*)P.x;
  float4* o4 = (float4*)P.o_arr;
  CoefReg C = load_coefs(P, tg);
  float4 s = {0,0,0,0}, q = {0,0,0,0};
  #pragma unroll
  for (int r = 0; r < 8; ++r) {
    size_t base = (size_t)(r0 + r) * NG;
    float4 xq = x4[base + tg];
    float4 xk = x4[base + 256 + tg];
    float4 xv = x4[base + 512 + tg];
    float4 ov = contract4(xq, xk, xv, C);
    o4[(size_t)(r0 + r) * DG + tg] = ov;
    acc4(s, q, ov);
  }
  lds_s[slice][lane] = s;
  lds_q[slice][lane] = q;
  __syncthreads();
  float ssum = 0.f, ssq = 0.f;
  #pragma unroll
  for (int i = 0; i < 4; ++i) {
    ssum += ((const float*)&lds_s[i][t >> 2])[t & 3];
    ssq  += ((const float*)&lds_q[i][t >> 2])[t & 3];
  }
  atomicAdd(&P.osum[blockIdx.x * 256 + t], ssum);
  atomicAdd(&P.osq[blockIdx.x * 256 + t], ssq);
}

// ============ K4: per-thread stats recompute + normalize + write ============
// grid 2048, block 256 (4 rows/block). Each thread derives its own m/sc
// from the 8 KB accumulators (L2-hit) -- no separate stats kernel.
__global__ __launch_bounds__(256, 8) void k4_final(Params P) {
  const int t = threadIdx.x;
  float4 s4 = ((const float4*)P.osum)[t];
  float4 q4 = ((const float4*)P.osq)[t];
  float4 g4 = ((const float4*)P.g_out)[t];
  float4 b4 = ((const float4*)P.b_out)[t];
  float4 m, sc;
  #pragma unroll
  for (int kk = 0; kk < 4; ++kk) {
    float mean = ((const float*)&s4)[kk] / NROWS;
    float var = ((const float*)&q4)[kk] / NROWS - mean * mean;
    if (var < 0.f) var = 0.f;
    ((float*)&m)[kk] = mean;
    ((float*)&sc)[kk] = ((const float*)&g4)[kk] / sqrtf(var + EPS_NORM);
  }
  const int r0 = blockIdx.x * 4;
  const float4* o4 = (const float4*)P.o_arr;
  float4* out4 = (float4*)P.out;
  #pragma unroll
  for (int rr = 0; rr < 4; ++rr) {
    size_t idx = (size_t)(r0 + rr) * DG + t;
    float4 o = o4[idx];
    nfloat4 y;
    y.x = (o.x - m.x) * sc.x + b4.x;
    y.y = (o.y - m.y) * sc.y + b4.y;
    y.z = (o.z - m.z) * sc.z + b4.z;
    y.w = (o.w - m.w) * sc.w + b4.w;
    __builtin_nontemporal_store(y, (nfloat4*)&out4[idx]);
  }
}

}  // namespace

extern "C" void kernel_launch(void* const* d_in, const int* in_sizes, int n_in,
                              void* d_out, int out_size, void* d_ws, size_t ws_size,
                              hipStream_t stream) {
  Params P;
  P.x     = (const float*)d_in[0];
  P.wq    = (const float*)d_in[1];
  P.aq    = (const float*)d_in[3];
  P.gq    = (const float*)d_in[4];
  P.betaq = (const float*)d_in[5];
  P.wk    = (const float*)d_in[6];
  P.ak    = (const float*)d_in[8];
  P.gk    = (const float*)d_in[9];
  P.betak = (const float*)d_in[10];
  P.wv    = (const float*)d_in[11];
  P.av    = (const float*)d_in[13];
  P.gv    = (const float*)d_in[14];
  P.betav = (const float*)d_in[15];
  P.g_out = (const float*)d_in[16];
  P.b_out = (const float*)d_in[17];
  P.out   = (float*)d_out;

  float* ws = (float*)d_ws;
  // accumulators contiguous -> one memset
  P.colsum = ws;  ws += NC;
  P.colsq  = ws;  ws += NC;
  P.osum   = ws;  ws += DD;
  P.osq    = ws;  ws += DD;
  P.A_arr  = ws;  ws += 3 * NC;
  P.B_arr  = ws;  ws += 3 * NC;
  P.o_arr  = ws;  ws += (size_t)NROWS * DD;   // 32 MB

  (void)hipMemsetAsync(P.colsum, 0, (2 * NC + 2 * DD) * sizeof(float), stream);
  k1_col_stats<<<dim3(12, 64), dim3(256), 0, stream>>>(P);
  k2_coef<<<dim3(12), dim3(256), 0, stream>>>(P);
  k3_main<<<dim3(4, 256), dim3(256), 0, stream>>>(P);
  k4_final<<<dim3(2048), dim3(256), 0, stream>>>(P);
}